// Round 19
// baseline (6527.015 us; speedup 1.0000x reference)
//
#include <hip/hip_runtime.h>
#include <hip/hip_bf16.h>
#include <math.h>

// build h19 = g18 + LDS-staged x in the tail (kills the remaining VGPR spill:
// g18_tail FETCH 13.4 GB / WRITE 3.8 GB vs 93 MB ideal).
#define XYZ 135168   // 64*64*33
#define W 20
#define NMODE 2048   // 16*16*8
#define NREAL 3584   // 16*16*14

__device__ __forceinline__ float h19_gelu(float v) {
    return 0.5f * v * (1.0f + erff(v * 0.7071067811865476f));
}

__global__ __launch_bounds__(256, 2)
void h19_fc0(const float* __restrict__ xr_in, const float* __restrict__ xi_in,
             const float* __restrict__ fr, const float* __restrict__ fi,
             float* __restrict__ xre, float* __restrict__ xim) {
    int idx = blockIdx.x * blockDim.x + threadIdx.x;
    if (idx >= 4 * XYZ) return;
    int b = idx / XYZ, p = idx % XYZ;
    float ar[3], ai[3];
#pragma unroll
    for (int i = 0; i < 3; i++) {
        ar[i] = xr_in[(size_t)(b * 3 + i) * XYZ + p];
        ai[i] = xi_in[(size_t)(b * 3 + i) * XYZ + p];
    }
#pragma unroll
    for (int o = 0; o < W; o++) {
        float rr = 0.f, ii = 0.f;
#pragma unroll
        for (int i = 0; i < 3; i++) {
            float wr = fr[i * W + o], wi = fi[i * W + o];
            rr += ar[i] * wr - ai[i] * wi;
            ii += ar[i] * wi + ai[i] * wr;
        }
        xre[(size_t)(b * W + o) * XYZ + p] = rr;
        xim[(size_t)(b * W + o) * XYZ + p] = ii;
    }
}

__global__ __launch_bounds__(256, 2)
void h19_gifftx(const float* __restrict__ xre, const float* __restrict__ xim,
                float* __restrict__ are, float* __restrict__ aim) {
    int t = blockIdx.x * blockDim.x + threadIdx.x;
    if (t >= 80 * NMODE) return;
    int kz = t & 7, ky = (t >> 3) & 15, nx = (t >> 7) & 15, bc = t >> 11;
    int col = (ky < 8) ? ky : ky + 48;
    const float* pr = xre + (size_t)bc * XYZ;
    const float* pi = xim + (size_t)bc * XYZ;
    float accr = 0.f, acci = 0.f;
    for (int kx = 0; kx < 16; kx++) {
        int row = (kx < 8) ? kx : kx + 48;
        int off = (row * 64 + col) * 33 + kz;
        float vr = pr[off], vi = pi[off];
        int m = (kx * nx) & 15;
        float s, c;
        sincosf((float)m * 0.39269908169872414f, &s, &c);
        accr += vr * c - vi * s;
        acci += vr * s + vi * c;
    }
    are[t] = accr * 0.0625f;
    aim[t] = acci * 0.0625f;
}

__global__ __launch_bounds__(256, 2)
void h19_iffty(const float* __restrict__ are, const float* __restrict__ aim,
               float* __restrict__ bre, float* __restrict__ bim) {
    int t = blockIdx.x * blockDim.x + threadIdx.x;
    if (t >= 80 * NMODE) return;
    int kz = t & 7, ny = (t >> 3) & 15, nx = (t >> 7) & 15, bc = t >> 11;
    int base = ((bc * 16 + nx) * 16) * 8 + kz;
    float accr = 0.f, acci = 0.f;
    for (int ky = 0; ky < 16; ky++) {
        float vr = are[base + ky * 8], vi = aim[base + ky * 8];
        int m = (ky * ny) & 15;
        float s, c;
        sincosf((float)m * 0.39269908169872414f, &s, &c);
        accr += vr * c - vi * s;
        acci += vr * s + vi * c;
    }
    bre[t] = accr * 0.0625f;
    bim[t] = acci * 0.0625f;
}

__global__ __launch_bounds__(256, 2)
void h19_irfftz(const float* __restrict__ bre, const float* __restrict__ bim,
                float* __restrict__ r1) {
    int t = blockIdx.x * blockDim.x + threadIdx.x;
    if (t >= 80 * NREAL) return;
    int nz = t % 14;
    int q = t / 14;
    int base = q * 8;
    float acc = bre[base];
    float re7 = bre[base + 7];
    acc += (nz & 1) ? -re7 : re7;
    for (int k = 1; k < 7; k++) {
        int m = (k * nz) % 14;
        float s, c;
        sincosf((float)m * 0.4487989505128276f, &s, &c);
        acc += 2.f * (bre[base + k] * c - bim[base + k] * s);
    }
    r1[t] = acc * (1.0f / 14.0f);
}

__global__ __launch_bounds__(256, 2)
void h19_mix(const float* __restrict__ r1, const float* __restrict__ wconv,
             int l, float* __restrict__ r2) {
    int t = blockIdx.x * blockDim.x + threadIdx.x;
    if (t >= 80 * NREAL) return;
    int p = t % NREAL;
    int o = (t / NREAL) % W;
    int b = t / (NREAL * W);
    const float* wl = wconv + (size_t)l * W * W * NREAL;
    float acc = 0.f;
#pragma unroll
    for (int i = 0; i < W; i++)
        acc += r1[(size_t)(b * W + i) * NREAL + p] * wl[(size_t)(i * W + o) * NREAL + p];
    r2[t] = acc;
}

__global__ __launch_bounds__(256, 2)
void h19_rfftz(const float* __restrict__ r2,
               float* __restrict__ are, float* __restrict__ aim) {
    int t = blockIdx.x * blockDim.x + threadIdx.x;
    if (t >= 80 * NMODE) return;
    int k = t & 7;
    int q = t >> 3;
    int base = q * 14;
    float accr = 0.f, acci = 0.f;
    for (int n = 0; n < 14; n++) {
        float v = r2[base + n];
        int m = (k * n) % 14;
        float s, c;
        sincosf((float)m * 0.4487989505128276f, &s, &c);
        accr += v * c;
        acci -= v * s;
    }
    are[t] = accr;
    aim[t] = acci;
}

__global__ __launch_bounds__(256, 2)
void h19_fftx(const float* __restrict__ are, const float* __restrict__ aim,
              float* __restrict__ bre, float* __restrict__ bim) {
    int t = blockIdx.x * blockDim.x + threadIdx.x;
    if (t >= 80 * NMODE) return;
    int kz = t & 7, ny = (t >> 3) & 15, kx = (t >> 7) & 15, bc = t >> 11;
    int base = bc * 2048 + ny * 8 + kz;
    float accr = 0.f, acci = 0.f;
    for (int nx = 0; nx < 16; nx++) {
        float vr = are[base + nx * 128], vi = aim[base + nx * 128];
        int m = (kx * nx) & 15;
        float s, c;
        sincosf((float)m * 0.39269908169872414f, &s, &c);
        accr += vr * c + vi * s;
        acci += vi * c - vr * s;
    }
    bre[t] = accr;
    bim[t] = acci;
}

__global__ __launch_bounds__(256, 2)
void h19_ffty(const float* __restrict__ bre, const float* __restrict__ bim,
              float* __restrict__ are, float* __restrict__ aim) {
    int t = blockIdx.x * blockDim.x + threadIdx.x;
    if (t >= 80 * NMODE) return;
    int kz = t & 7, ky = (t >> 3) & 15, kx = (t >> 7) & 15, bc = t >> 11;
    int base = bc * 2048 + kx * 128 + kz;
    float accr = 0.f, acci = 0.f;
    for (int ny = 0; ny < 16; ny++) {
        float vr = bre[base + ny * 8], vi = bim[base + ny * 8];
        int m = (ky * ny) & 15;
        float s, c;
        sincosf((float)m * 0.39269908169872414f, &s, &c);
        accr += vr * c + vi * s;
        acci += vi * c - vr * s;
    }
    are[t] = accr;
    aim[t] = acci;
}

__global__ __launch_bounds__(256, 2)
void h19_combine(float* __restrict__ xre, float* __restrict__ xim,
                 const float* __restrict__ ere, const float* __restrict__ eim,
                 const float* __restrict__ wpt_r, const float* __restrict__ wpt_i,
                 int l, const float* __restrict__ smooth, int apply_gelu) {
    __shared__ float wr[W * W], wi[W * W];
    for (int i = threadIdx.x; i < W * W; i += blockDim.x) {
        wr[i] = wpt_r[l * W * W + i];
        wi[i] = wpt_i[l * W * W + i];
    }
    __syncthreads();
    int idx = blockIdx.x * blockDim.x + threadIdx.x;
    if (idx >= 4 * XYZ) return;
    int b = idx / XYZ, p = idx % XYZ;
    int gz = p % 33;
    int gxy = p / 33;
    int gy = gxy & 63;
    int gx = gxy >> 6;
    int kx = (gx < 8) ? gx : ((gx >= 56) ? gx - 48 : -1);
    int ky = (gy < 8) ? gy : ((gy >= 56) ? gy - 48 : -1);
    bool corner = (kx >= 0) && (ky >= 0) && (gz < 8);
    float sm = smooth[p];
    float ar[W], ai[W];
#pragma unroll
    for (int i = 0; i < W; i++) {
        ar[i] = xre[(size_t)(b * W + i) * XYZ + p];
        ai[i] = xim[(size_t)(b * W + i) * XYZ + p];
    }
    int ebase = corner ? (b * W * NMODE + (kx * 16 + ky) * 8 + gz) : 0;
    for (int o = 0; o < W; o++) {
        float rr = 0.f, ii = 0.f;
#pragma unroll
        for (int i = 0; i < W; i++) {
            float wwr = wr[i * W + o], wwi = wi[i * W + o];
            rr += ar[i] * wwr - ai[i] * wwi;
            ii += ar[i] * wwi + ai[i] * wwr;
        }
        if (corner) {
            rr += ere[ebase + o * NMODE];
            ii += eim[ebase + o * NMODE];
        }
        rr *= sm;
        ii *= sm;
        if (apply_gelu) {
            rr = h19_gelu(rr);
            ii = h19_gelu(ii);
        }
        xre[(size_t)(b * W + o) * XYZ + p] = rr;
        xim[(size_t)(b * W + o) * XYZ + p] = ii;
    }
}

// tail: fc1 (20->128) -> cgelu -> fc2 (128->3), real-only output.
// x staged in LDS (40 KB) so nothing big lives in registers across the jc loop.
// Static LDS: 40960(x) + 20480(w1) + 3072(w2) = 64512 B <= 64 KB block cap.
__global__ __launch_bounds__(256, 2)
void h19_tail(const float* __restrict__ xre, const float* __restrict__ xim,
              const float* __restrict__ f1r, const float* __restrict__ f1i,
              const float* __restrict__ f2r, const float* __restrict__ f2i,
              float* __restrict__ outf) {
    __shared__ __align__(16) float w1r[W * 128], w1i[W * 128];
    __shared__ __align__(16) float w2r[3 * 128], w2i[3 * 128];
    __shared__ float sxr[W * 256], sxi[W * 256];
    int tid = threadIdx.x;
    for (int i = tid; i < W * 128; i += blockDim.x) {
        w1r[i] = f1r[i];
        w1i[i] = f1i[i];
    }
    for (int i = tid; i < 3 * 128; i += blockDim.x) {
        int j = i & 127, o = i >> 7;
        w2r[o * 128 + j] = f2r[j * 3 + o];
        w2i[o * 128 + j] = f2i[j * 3 + o];
    }
    int idx = blockIdx.x * blockDim.x + tid;
    int b = idx / XYZ, p = idx % XYZ;
#pragma unroll
    for (int i = 0; i < W; i++) {
        sxr[i * 256 + tid] = xre[(size_t)(b * W + i) * XYZ + p];
        sxi[i * 256 + tid] = xim[(size_t)(b * W + i) * XYZ + p];
    }
    __syncthreads();

    float accr[3] = {0.f, 0.f, 0.f};
    for (int jc = 0; jc < 16; jc++) {
        int jb = jc * 8;
        float tr[8], ti[8];
#pragma unroll
        for (int jj = 0; jj < 8; jj++) { tr[jj] = 0.f; ti[jj] = 0.f; }
#pragma unroll
        for (int i = 0; i < W; i++) {
            float4 wrA = *(const float4*)&w1r[i * 128 + jb];
            float4 wrB = *(const float4*)&w1r[i * 128 + jb + 4];
            float4 wiA = *(const float4*)&w1i[i * 128 + jb];
            float4 wiB = *(const float4*)&w1i[i * 128 + jb + 4];
            float xr_ = sxr[i * 256 + tid];
            float xi_ = sxi[i * 256 + tid];
            tr[0] += xr_ * wrA.x - xi_ * wiA.x;  ti[0] += xr_ * wiA.x + xi_ * wrA.x;
            tr[1] += xr_ * wrA.y - xi_ * wiA.y;  ti[1] += xr_ * wiA.y + xi_ * wrA.y;
            tr[2] += xr_ * wrA.z - xi_ * wiA.z;  ti[2] += xr_ * wiA.z + xi_ * wrA.z;
            tr[3] += xr_ * wrA.w - xi_ * wiA.w;  ti[3] += xr_ * wiA.w + xi_ * wrA.w;
            tr[4] += xr_ * wrB.x - xi_ * wiB.x;  ti[4] += xr_ * wiB.x + xi_ * wrB.x;
            tr[5] += xr_ * wrB.y - xi_ * wiB.y;  ti[5] += xr_ * wiB.y + xi_ * wrB.y;
            tr[6] += xr_ * wrB.z - xi_ * wiB.z;  ti[6] += xr_ * wiB.z + xi_ * wrB.z;
            tr[7] += xr_ * wrB.w - xi_ * wiB.w;  ti[7] += xr_ * wiB.w + xi_ * wrB.w;
        }
#pragma unroll
        for (int jj = 0; jj < 8; jj++) {
            tr[jj] = h19_gelu(tr[jj]);
            ti[jj] = h19_gelu(ti[jj]);
        }
#pragma unroll
        for (int o = 0; o < 3; o++) {
            float4 crA = *(const float4*)&w2r[o * 128 + jb];
            float4 crB = *(const float4*)&w2r[o * 128 + jb + 4];
            float4 ciA = *(const float4*)&w2i[o * 128 + jb];
            float4 ciB = *(const float4*)&w2i[o * 128 + jb + 4];
            accr[o] += tr[0] * crA.x - ti[0] * ciA.x;
            accr[o] += tr[1] * crA.y - ti[1] * ciA.y;
            accr[o] += tr[2] * crA.z - ti[2] * ciA.z;
            accr[o] += tr[3] * crA.w - ti[3] * ciA.w;
            accr[o] += tr[4] * crB.x - ti[4] * ciB.x;
            accr[o] += tr[5] * crB.y - ti[5] * ciB.y;
            accr[o] += tr[6] * crB.z - ti[6] * ciB.z;
            accr[o] += tr[7] * crB.w - ti[7] * ciB.w;
        }
    }
#pragma unroll
    for (int o = 0; o < 3; o++) {
        size_t k = (size_t)(b * 3 + o) * XYZ + p;
        outf[k] = __bfloat162float(__float2bfloat16(accr[o]));
    }
}

extern "C" void kernel_launch(void* const* d_in, const int* in_sizes, int n_in,
                              void* d_out, int out_size, void* d_ws, size_t ws_size,
                              hipStream_t stream) {
    const float* x_r    = (const float*)d_in[0];
    const float* x_i    = (const float*)d_in[1];
    const float* smooth = (const float*)d_in[2];
    const float* wconv  = (const float*)d_in[3];
    const float* wpt_r  = (const float*)d_in[4];
    const float* wpt_i  = (const float*)d_in[5];
    const float* fc0_r  = (const float*)d_in[6];
    const float* fc0_i  = (const float*)d_in[7];
    const float* fc1_r  = (const float*)d_in[8];
    const float* fc1_i  = (const float*)d_in[9];
    const float* fc2_r  = (const float*)d_in[10];
    const float* fc2_i  = (const float*)d_in[11];
    float* outf = (float*)d_out;

    const size_t NBW = (size_t)4 * W * XYZ;
    const size_t NM  = (size_t)80 * NMODE;
    const size_t NR  = (size_t)80 * NREAL;
    const size_t modeFloats = 4 * NM + 2 * NR;

    float* modebuf = (float*)d_ws;
    float* are = modebuf;
    float* aim = are + NM;
    float* bre = aim + NM;
    float* bim = bre + NM;
    float* r1  = bim + NM;
    float* r2  = r1 + NR;
    float* xre = modebuf + modeFloats;
    float* xim = xre + NBW;

    dim3 blk(256);
    const int gP = (4 * XYZ) / 256;
    const int gM = (80 * NMODE) / 256;
    const int gR = (80 * NREAL) / 256;

    h19_fc0<<<gP, blk, 0, stream>>>(x_r, x_i, fc0_r, fc0_i, xre, xim);
    for (int l = 0; l < 4; l++) {
        h19_gifftx<<<gM, blk, 0, stream>>>(xre, xim, are, aim);
        h19_iffty<<<gM, blk, 0, stream>>>(are, aim, bre, bim);
        h19_irfftz<<<gR, blk, 0, stream>>>(bre, bim, r1);
        h19_mix<<<gR, blk, 0, stream>>>(r1, wconv, l, r2);
        h19_rfftz<<<gM, blk, 0, stream>>>(r2, are, aim);
        h19_fftx<<<gM, blk, 0, stream>>>(are, aim, bre, bim);
        h19_ffty<<<gM, blk, 0, stream>>>(bre, bim, are, aim);
        h19_combine<<<gP, blk, 0, stream>>>(xre, xim, are, aim, wpt_r, wpt_i, l,
                                            smooth, (l < 3) ? 1 : 0);
    }
    h19_tail<<<gP, blk, 0, stream>>>(xre, xim, fc1_r, fc1_i, fc2_r, fc2_i, outf);
}

// Round 20
// 749.417 us; speedup vs baseline: 8.7095x; 8.7095x over previous
//
#include <hip/hip_runtime.h>
#include <hip/hip_bf16.h>
#include <math.h>

// build k20 = g18 + inline erf (no libcall -> no caller-save spills) +
// #pragma unroll 1 on the tail channel loop (no hoisting pressure).
#define XYZ 135168   // 64*64*33
#define W 20
#define NMODE 2048   // 16*16*8
#define NREAL 3584   // 16*16*14

// erf via Abramowitz-Stegun 7.1.26 (|eps| <= 1.5e-7), fully inline.
__device__ __forceinline__ float k20_erf(float x) {
    float s = (x < 0.f) ? -1.f : 1.f;
    float a = fabsf(x);
    float t = 1.f / fmaf(0.3275911f, a, 1.f);
    float poly = t * fmaf(t, fmaf(t, fmaf(t, fmaf(t, 1.061405429f, -1.453152027f),
                                           1.421413741f), -0.284496736f), 0.254829592f);
    float e = __expf(-a * a);
    return s * (1.f - poly * e);
}
__device__ __forceinline__ float k20_gelu(float v) {
    return 0.5f * v * (1.0f + k20_erf(v * 0.7071067811865476f));
}

__global__ __launch_bounds__(256, 2)
void k20_fc0(const float* __restrict__ xr_in, const float* __restrict__ xi_in,
             const float* __restrict__ fr, const float* __restrict__ fi,
             float* __restrict__ xre, float* __restrict__ xim) {
    int idx = blockIdx.x * blockDim.x + threadIdx.x;
    if (idx >= 4 * XYZ) return;
    int b = idx / XYZ, p = idx % XYZ;
    float ar[3], ai[3];
#pragma unroll
    for (int i = 0; i < 3; i++) {
        ar[i] = xr_in[(size_t)(b * 3 + i) * XYZ + p];
        ai[i] = xi_in[(size_t)(b * 3 + i) * XYZ + p];
    }
#pragma unroll
    for (int o = 0; o < W; o++) {
        float rr = 0.f, ii = 0.f;
#pragma unroll
        for (int i = 0; i < 3; i++) {
            float wr = fr[i * W + o], wi = fi[i * W + o];
            rr += ar[i] * wr - ai[i] * wi;
            ii += ar[i] * wi + ai[i] * wr;
        }
        xre[(size_t)(b * W + o) * XYZ + p] = rr;
        xim[(size_t)(b * W + o) * XYZ + p] = ii;
    }
}

__global__ __launch_bounds__(256, 2)
void k20_gifftx(const float* __restrict__ xre, const float* __restrict__ xim,
                float* __restrict__ are, float* __restrict__ aim) {
    int t = blockIdx.x * blockDim.x + threadIdx.x;
    if (t >= 80 * NMODE) return;
    int kz = t & 7, ky = (t >> 3) & 15, nx = (t >> 7) & 15, bc = t >> 11;
    int col = (ky < 8) ? ky : ky + 48;
    const float* pr = xre + (size_t)bc * XYZ;
    const float* pi = xim + (size_t)bc * XYZ;
    float accr = 0.f, acci = 0.f;
    for (int kx = 0; kx < 16; kx++) {
        int row = (kx < 8) ? kx : kx + 48;
        int off = (row * 64 + col) * 33 + kz;
        float vr = pr[off], vi = pi[off];
        int m = (kx * nx) & 15;
        float s, c;
        sincosf((float)m * 0.39269908169872414f, &s, &c);
        accr += vr * c - vi * s;
        acci += vr * s + vi * c;
    }
    are[t] = accr * 0.0625f;
    aim[t] = acci * 0.0625f;
}

__global__ __launch_bounds__(256, 2)
void k20_iffty(const float* __restrict__ are, const float* __restrict__ aim,
               float* __restrict__ bre, float* __restrict__ bim) {
    int t = blockIdx.x * blockDim.x + threadIdx.x;
    if (t >= 80 * NMODE) return;
    int kz = t & 7, ny = (t >> 3) & 15, nx = (t >> 7) & 15, bc = t >> 11;
    int base = ((bc * 16 + nx) * 16) * 8 + kz;
    float accr = 0.f, acci = 0.f;
    for (int ky = 0; ky < 16; ky++) {
        float vr = are[base + ky * 8], vi = aim[base + ky * 8];
        int m = (ky * ny) & 15;
        float s, c;
        sincosf((float)m * 0.39269908169872414f, &s, &c);
        accr += vr * c - vi * s;
        acci += vr * s + vi * c;
    }
    bre[t] = accr * 0.0625f;
    bim[t] = acci * 0.0625f;
}

__global__ __launch_bounds__(256, 2)
void k20_irfftz(const float* __restrict__ bre, const float* __restrict__ bim,
                float* __restrict__ r1) {
    int t = blockIdx.x * blockDim.x + threadIdx.x;
    if (t >= 80 * NREAL) return;
    int nz = t % 14;
    int q = t / 14;
    int base = q * 8;
    float acc = bre[base];
    float re7 = bre[base + 7];
    acc += (nz & 1) ? -re7 : re7;
    for (int k = 1; k < 7; k++) {
        int m = (k * nz) % 14;
        float s, c;
        sincosf((float)m * 0.4487989505128276f, &s, &c);
        acc += 2.f * (bre[base + k] * c - bim[base + k] * s);
    }
    r1[t] = acc * (1.0f / 14.0f);
}

__global__ __launch_bounds__(256, 2)
void k20_mix(const float* __restrict__ r1, const float* __restrict__ wconv,
             int l, float* __restrict__ r2) {
    int t = blockIdx.x * blockDim.x + threadIdx.x;
    if (t >= 80 * NREAL) return;
    int p = t % NREAL;
    int o = (t / NREAL) % W;
    int b = t / (NREAL * W);
    const float* wl = wconv + (size_t)l * W * W * NREAL;
    float acc = 0.f;
#pragma unroll
    for (int i = 0; i < W; i++)
        acc += r1[(size_t)(b * W + i) * NREAL + p] * wl[(size_t)(i * W + o) * NREAL + p];
    r2[t] = acc;
}

__global__ __launch_bounds__(256, 2)
void k20_rfftz(const float* __restrict__ r2,
               float* __restrict__ are, float* __restrict__ aim) {
    int t = blockIdx.x * blockDim.x + threadIdx.x;
    if (t >= 80 * NMODE) return;
    int k = t & 7;
    int q = t >> 3;
    int base = q * 14;
    float accr = 0.f, acci = 0.f;
    for (int n = 0; n < 14; n++) {
        float v = r2[base + n];
        int m = (k * n) % 14;
        float s, c;
        sincosf((float)m * 0.4487989505128276f, &s, &c);
        accr += v * c;
        acci -= v * s;
    }
    are[t] = accr;
    aim[t] = acci;
}

__global__ __launch_bounds__(256, 2)
void k20_fftx(const float* __restrict__ are, const float* __restrict__ aim,
              float* __restrict__ bre, float* __restrict__ bim) {
    int t = blockIdx.x * blockDim.x + threadIdx.x;
    if (t >= 80 * NMODE) return;
    int kz = t & 7, ny = (t >> 3) & 15, kx = (t >> 7) & 15, bc = t >> 11;
    int base = bc * 2048 + ny * 8 + kz;
    float accr = 0.f, acci = 0.f;
    for (int nx = 0; nx < 16; nx++) {
        float vr = are[base + nx * 128], vi = aim[base + nx * 128];
        int m = (kx * nx) & 15;
        float s, c;
        sincosf((float)m * 0.39269908169872414f, &s, &c);
        accr += vr * c + vi * s;
        acci += vi * c - vr * s;
    }
    bre[t] = accr;
    bim[t] = acci;
}

__global__ __launch_bounds__(256, 2)
void k20_ffty(const float* __restrict__ bre, const float* __restrict__ bim,
              float* __restrict__ are, float* __restrict__ aim) {
    int t = blockIdx.x * blockDim.x + threadIdx.x;
    if (t >= 80 * NMODE) return;
    int kz = t & 7, ky = (t >> 3) & 15, kx = (t >> 7) & 15, bc = t >> 11;
    int base = bc * 2048 + kx * 128 + kz;
    float accr = 0.f, acci = 0.f;
    for (int ny = 0; ny < 16; ny++) {
        float vr = bre[base + ny * 8], vi = bim[base + ny * 8];
        int m = (ky * ny) & 15;
        float s, c;
        sincosf((float)m * 0.39269908169872414f, &s, &c);
        accr += vr * c + vi * s;
        acci += vi * c - vr * s;
    }
    are[t] = accr;
    aim[t] = acci;
}

__global__ __launch_bounds__(256, 2)
void k20_combine(float* __restrict__ xre, float* __restrict__ xim,
                 const float* __restrict__ ere, const float* __restrict__ eim,
                 const float* __restrict__ wpt_r, const float* __restrict__ wpt_i,
                 int l, const float* __restrict__ smooth, int apply_gelu) {
    __shared__ float wr[W * W], wi[W * W];
    for (int i = threadIdx.x; i < W * W; i += blockDim.x) {
        wr[i] = wpt_r[l * W * W + i];
        wi[i] = wpt_i[l * W * W + i];
    }
    __syncthreads();
    int idx = blockIdx.x * blockDim.x + threadIdx.x;
    if (idx >= 4 * XYZ) return;
    int b = idx / XYZ, p = idx % XYZ;
    int gz = p % 33;
    int gxy = p / 33;
    int gy = gxy & 63;
    int gx = gxy >> 6;
    int kx = (gx < 8) ? gx : ((gx >= 56) ? gx - 48 : -1);
    int ky = (gy < 8) ? gy : ((gy >= 56) ? gy - 48 : -1);
    bool corner = (kx >= 0) && (ky >= 0) && (gz < 8);
    float sm = smooth[p];
    float ar[W], ai[W];
#pragma unroll
    for (int i = 0; i < W; i++) {
        ar[i] = xre[(size_t)(b * W + i) * XYZ + p];
        ai[i] = xim[(size_t)(b * W + i) * XYZ + p];
    }
    int ebase = corner ? (b * W * NMODE + (kx * 16 + ky) * 8 + gz) : 0;
    for (int o = 0; o < W; o++) {
        float rr = 0.f, ii = 0.f;
#pragma unroll
        for (int i = 0; i < W; i++) {
            float wwr = wr[i * W + o], wwi = wi[i * W + o];
            rr += ar[i] * wwr - ai[i] * wwi;
            ii += ar[i] * wwi + ai[i] * wwr;
        }
        if (corner) {
            rr += ere[ebase + o * NMODE];
            ii += eim[ebase + o * NMODE];
        }
        rr *= sm;
        ii *= sm;
        if (apply_gelu) {
            rr = k20_gelu(rr);
            ii = k20_gelu(ii);
        }
        xre[(size_t)(b * W + o) * XYZ + p] = rr;
        xim[(size_t)(b * W + o) * XYZ + p] = ii;
    }
}

// tail: fc1 (20->128) -> cgelu -> fc2 (128->3), real-only float32 output.
// x in registers; i-loop NOT unrolled (no hoisting pressure); inline gelu.
__global__ __launch_bounds__(256, 2)
void k20_tail(const float* __restrict__ xre, const float* __restrict__ xim,
              const float* __restrict__ f1r, const float* __restrict__ f1i,
              const float* __restrict__ f2r, const float* __restrict__ f2i,
              float* __restrict__ outf) {
    __shared__ __align__(16) float w1r[W * 128], w1i[W * 128];
    __shared__ __align__(16) float w2r[3 * 128], w2i[3 * 128];
    for (int i = threadIdx.x; i < W * 128; i += blockDim.x) {
        w1r[i] = f1r[i];
        w1i[i] = f1i[i];
    }
    for (int i = threadIdx.x; i < 3 * 128; i += blockDim.x) {
        int j = i & 127, o = i >> 7;
        w2r[o * 128 + j] = f2r[j * 3 + o];
        w2i[o * 128 + j] = f2i[j * 3 + o];
    }
    __syncthreads();
    int idx = blockIdx.x * blockDim.x + threadIdx.x;
    if (idx >= 4 * XYZ) return;
    int b = idx / XYZ, p = idx % XYZ;
    float ar[W], ai[W];
#pragma unroll
    for (int i = 0; i < W; i++) {
        ar[i] = xre[(size_t)(b * W + i) * XYZ + p];
        ai[i] = xim[(size_t)(b * W + i) * XYZ + p];
    }
    float accr[3] = {0.f, 0.f, 0.f};
    for (int jc = 0; jc < 16; jc++) {
        int jb = jc * 8;
        float tr[8], ti[8];
#pragma unroll
        for (int jj = 0; jj < 8; jj++) { tr[jj] = 0.f; ti[jj] = 0.f; }
#pragma unroll 1
        for (int i = 0; i < W; i++) {
            float4 wrA = *(const float4*)&w1r[i * 128 + jb];
            float4 wrB = *(const float4*)&w1r[i * 128 + jb + 4];
            float4 wiA = *(const float4*)&w1i[i * 128 + jb];
            float4 wiB = *(const float4*)&w1i[i * 128 + jb + 4];
            float xr_ = ar[i], xi_ = ai[i];
            tr[0] += xr_ * wrA.x - xi_ * wiA.x;  ti[0] += xr_ * wiA.x + xi_ * wrA.x;
            tr[1] += xr_ * wrA.y - xi_ * wiA.y;  ti[1] += xr_ * wiA.y + xi_ * wrA.y;
            tr[2] += xr_ * wrA.z - xi_ * wiA.z;  ti[2] += xr_ * wiA.z + xi_ * wrA.z;
            tr[3] += xr_ * wrA.w - xi_ * wiA.w;  ti[3] += xr_ * wiA.w + xi_ * wrA.w;
            tr[4] += xr_ * wrB.x - xi_ * wiB.x;  ti[4] += xr_ * wiB.x + xi_ * wrB.x;
            tr[5] += xr_ * wrB.y - xi_ * wiB.y;  ti[5] += xr_ * wiB.y + xi_ * wrB.y;
            tr[6] += xr_ * wrB.z - xi_ * wiB.z;  ti[6] += xr_ * wiB.z + xi_ * wrB.z;
            tr[7] += xr_ * wrB.w - xi_ * wiB.w;  ti[7] += xr_ * wiB.w + xi_ * wrB.w;
        }
#pragma unroll
        for (int jj = 0; jj < 8; jj++) {
            tr[jj] = k20_gelu(tr[jj]);
            ti[jj] = k20_gelu(ti[jj]);
        }
#pragma unroll
        for (int o = 0; o < 3; o++) {
            float4 crA = *(const float4*)&w2r[o * 128 + jb];
            float4 crB = *(const float4*)&w2r[o * 128 + jb + 4];
            float4 ciA = *(const float4*)&w2i[o * 128 + jb];
            float4 ciB = *(const float4*)&w2i[o * 128 + jb + 4];
            accr[o] += tr[0] * crA.x - ti[0] * ciA.x;
            accr[o] += tr[1] * crA.y - ti[1] * ciA.y;
            accr[o] += tr[2] * crA.z - ti[2] * ciA.z;
            accr[o] += tr[3] * crA.w - ti[3] * ciA.w;
            accr[o] += tr[4] * crB.x - ti[4] * ciB.x;
            accr[o] += tr[5] * crB.y - ti[5] * ciB.y;
            accr[o] += tr[6] * crB.z - ti[6] * ciB.z;
            accr[o] += tr[7] * crB.w - ti[7] * ciB.w;
        }
    }
#pragma unroll
    for (int o = 0; o < 3; o++) {
        size_t k = (size_t)(b * 3 + o) * XYZ + p;
        outf[k] = __bfloat162float(__float2bfloat16(accr[o]));
    }
}

extern "C" void kernel_launch(void* const* d_in, const int* in_sizes, int n_in,
                              void* d_out, int out_size, void* d_ws, size_t ws_size,
                              hipStream_t stream) {
    const float* x_r    = (const float*)d_in[0];
    const float* x_i    = (const float*)d_in[1];
    const float* smooth = (const float*)d_in[2];
    const float* wconv  = (const float*)d_in[3];
    const float* wpt_r  = (const float*)d_in[4];
    const float* wpt_i  = (const float*)d_in[5];
    const float* fc0_r  = (const float*)d_in[6];
    const float* fc0_i  = (const float*)d_in[7];
    const float* fc1_r  = (const float*)d_in[8];
    const float* fc1_i  = (const float*)d_in[9];
    const float* fc2_r  = (const float*)d_in[10];
    const float* fc2_i  = (const float*)d_in[11];
    float* outf = (float*)d_out;

    const size_t NBW = (size_t)4 * W * XYZ;
    const size_t NM  = (size_t)80 * NMODE;
    const size_t NR  = (size_t)80 * NREAL;
    const size_t modeFloats = 4 * NM + 2 * NR;

    float* modebuf = (float*)d_ws;
    float* are = modebuf;
    float* aim = are + NM;
    float* bre = aim + NM;
    float* bim = bre + NM;
    float* r1  = bim + NM;
    float* r2  = r1 + NR;
    float* xre = modebuf + modeFloats;
    float* xim = xre + NBW;

    dim3 blk(256);
    const int gP = (4 * XYZ) / 256;
    const int gM = (80 * NMODE) / 256;
    const int gR = (80 * NREAL) / 256;

    k20_fc0<<<gP, blk, 0, stream>>>(x_r, x_i, fc0_r, fc0_i, xre, xim);
    for (int l = 0; l < 4; l++) {
        k20_gifftx<<<gM, blk, 0, stream>>>(xre, xim, are, aim);
        k20_iffty<<<gM, blk, 0, stream>>>(are, aim, bre, bim);
        k20_irfftz<<<gR, blk, 0, stream>>>(bre, bim, r1);
        k20_mix<<<gR, blk, 0, stream>>>(r1, wconv, l, r2);
        k20_rfftz<<<gM, blk, 0, stream>>>(r2, are, aim);
        k20_fftx<<<gM, blk, 0, stream>>>(are, aim, bre, bim);
        k20_ffty<<<gM, blk, 0, stream>>>(bre, bim, are, aim);
        k20_combine<<<gP, blk, 0, stream>>>(xre, xim, are, aim, wpt_r, wpt_i, l,
                                            smooth, (l < 3) ? 1 : 0);
    }
    k20_tail<<<gP, blk, 0, stream>>>(xre, xim, fc1_r, fc1_i, fc2_r, fc2_i, outf);
}